// Round 2
// baseline (852.253 us; speedup 1.0000x reference)
//
#include <hip/hip_runtime.h>

typedef __attribute__((ext_vector_type(8))) short short8;
typedef __attribute__((ext_vector_type(4))) float f32x4;
typedef __attribute__((ext_vector_type(4))) unsigned short us4;

#define LEAK 0.2f

__device__ __forceinline__ float b2f(unsigned short s) {
    unsigned u = ((unsigned)s) << 16;
    return __builtin_bit_cast(float, u);
}
__device__ __forceinline__ unsigned short f2b(float f) {
    unsigned u = __builtin_bit_cast(unsigned, f);
    u += 0x7fffu + ((u >> 16) & 1u);
    return (unsigned short)(u >> 16);
}

// async 16B global->LDS (direct-to-shared DMA). LDS base wave-uniform; HW adds lane*16.
__device__ __forceinline__ void async16(const short* g, short* l) {
    __builtin_amdgcn_global_load_lds(
        (const __attribute__((address_space(1))) void*)g,
        (__attribute__((address_space(3))) void*)l, 16, 0, 0);
}

// ---------------- prep: upsample / warp / cost volume (LDS-staged, coalesced) ----
// Block = 64 pixels of one row (quarter row). All global I/O is 16B/lane contiguous.
// vol: halo layout [B,130,258,144] bf16; interior pixel (h,w) -> row h+1, col w+1.
// ch 0..127 = left(bf16), 128..132 = costs, 133 = up, 134..143 = 0.
__global__ __launch_bounds__(256)
void prep_kernel(const float* __restrict__ left, const float* __restrict__ right,
                 const float* __restrict__ pd, short* __restrict__ vol) {
    __shared__ __align__(16) float inL[64 * 132];   // [px][128 ch + 4 pad]
    __shared__ __align__(16) float rrow[256];       // right row (b,h)
    __shared__ __align__(16) float pr0[128];        // pd row y0c
    __shared__ __align__(16) float pr1[128];        // pd row y1c
    __shared__ __align__(16) short outT[64 * 144];  // output tile

    int t = threadIdx.x;
    int blk = blockIdx.x;                 // 4096 = b(8) * h(128) * wq(4)
    int wq = blk & 3, h = (blk >> 2) & 127, b = blk >> 9;
    int w0 = wq << 6;

    // row-uniform upsample y terms
    float sy = h * 0.5f - 0.25f;
    float fy0 = floorf(sy);
    float fy = sy - fy0;
    int y0 = (int)fy0;
    int y0c = min(max(y0, 0), 63), y1c = min(max(y0 + 1, 0), 63);

    // ---- phase 1: coalesced loads -> LDS ----
    const float* lp = left + ((size_t)((b * 128 + h) * 256 + w0)) * 128;
#pragma unroll
    for (int k2 = 0; k2 < 8; ++k2) {
        int g = t + k2 * 256;             // granule 0..2047 (16B each)
        int p = g >> 5, j = g & 31;
        float4 v = *(const float4*)(lp + (size_t)g * 4);
        *(float4*)(&inL[p * 132 + j * 4]) = v;
    }
    if (t < 64) {
        *(float4*)(&rrow[t * 4]) =
            *(const float4*)(right + ((size_t)(b * 128 + h)) * 256 + t * 4);
    } else if (t < 96) {
        int i2 = t - 64;
        *(float4*)(&pr0[i2 * 4]) = *(const float4*)(pd + (size_t)(b * 64 + y0c) * 128 + i2 * 4);
    } else if (t < 128) {
        int i2 = t - 96;
        *(float4*)(&pr1[i2 * 4]) = *(const float4*)(pd + (size_t)(b * 64 + y1c) * 128 + i2 * 4);
    }
    __syncthreads();

    // ---- phase 2: 4 threads per pixel ----
    int p = t >> 2, s = t & 3;
    int w = w0 + p;
    const float* src = &inL[p * 132 + s * 32];
    short* odst = &outT[p * 144 + s * 32];
    float sum = 0.f;
#pragma unroll
    for (int i = 0; i < 8; ++i) {
        float f0 = src[i * 4], f1 = src[i * 4 + 1], f2 = src[i * 4 + 2], f3 = src[i * 4 + 3];
        sum += (f0 + f1) + (f2 + f3);
        us4 o;
        o.x = f2b(f0); o.y = f2b(f1); o.z = f2b(f2); o.w = f2b(f3);
        *(us4*)(odst + i * 4) = o;
    }
    sum += __shfl_xor(sum, 1);
    sum += __shfl_xor(sum, 2);
    float mean = sum * (1.f / 128.f);

    float one_fy = 1.f - fy;
#pragma unroll
    for (int tap = s; tap < 5; tap += 4) {   // s=0 -> taps 0,4; s=1,2,3 -> taps 1,2,3
        int jj = w + tap - 2;
        if (jj >= 0 && jj < 256) {
            float sx = jj * 0.5f - 0.25f;
            float fx0 = floorf(sx);
            float fx = sx - fx0;
            int x0 = (int)fx0;
            int x0c = min(max(x0, 0), 127), x1c = min(max(x0 + 1, 0), 127);
            float up = one_fy * ((1.f - fx) * pr0[x0c] + fx * pr0[x1c])
                     + fy     * ((1.f - fx) * pr1[x0c] + fx * pr1[x1c]);
            float cx = (float)jj - up;
            float xf0 = floorf(cx), xf1 = xf0 + 1.f;
            float w0x = xf1 - cx, w1x = cx - xf0;
            int ix0 = (int)fminf(fmaxf(xf0, 0.f), 255.f);
            int ix1 = (int)fminf(fmaxf(xf1, 0.f), 255.f);
            float warped = w0x * rrow[ix0] + w1x * rrow[ix1];
            outT[p * 144 + 128 + tap] = (short)f2b(warped * mean);
            if (tap == 2) outT[p * 144 + 133] = (short)f2b(up);   // jj==w always in-range
        } else {
            outT[p * 144 + 128 + tap] = 0;
        }
    }
    if (s == 0) { outT[p * 144 + 134] = 0; outT[p * 144 + 135] = 0; }
    if (s == 3) {
        us4 z = {};
        *(us4*)(&outT[p * 144 + 136]) = z;
        *(us4*)(&outT[p * 144 + 140]) = z;
    }
    __syncthreads();

    // ---- phase 3: coalesced store (tile is contiguous in halo layout) ----
    short* gdst = vol + ((size_t)(b * 130 + h + 1) * 258 + (w0 + 1)) * 144;
    for (int g = t; g < 1152; g += 256)
        *(short8*)(gdst + g * 8) = *(const short8*)(&outT[g * 8]);
}

// zero the halo ring of ONE buffer (schedule AFTER last reader of aliased layout)
__global__ void halo_zero_one(short* __restrict__ buf, int C) {
    int nchunk = C >> 3;
    int slot = blockIdx.x * 256 + threadIdx.x;
    int total = 8 * 772 * nchunk;
    if (slot >= total) return;
    int chunk = slot % nchunk;
    int pix = slot / nchunk;
    int b = pix / 772, p = pix % 772;
    int row, col;
    if (p < 516) { row = (p < 258) ? 0 : 129; col = (p < 258) ? p : p - 258; }
    else { int q = p - 516; row = 1 + (q >> 1); col = (q & 1) ? 257 : 0; }
    short8 z = {};
    *(short8*)(buf + ((size_t)(b * 130 + row) * 258 + col) * C + chunk * 8) = z;
}

// fp32 HWIO weights -> bf16 swizzled layout, all 5 layers in one launch.
// Layout (shorts): granule g = ((kc*9+tap)*COUT + n)*4 + s, where slot s holds
// k-quarter q = (s - n) & 3; within granule, 8 consecutive k (q*8..q*8+7).
// k zero-padded past CIN. Staged to LDS linearly; read with slot=(q+n)&3 ->
// conflict-free ds_read_b128 (granule&7 uniform across each quarter-wave).
__global__ void wconv_all(const float* __restrict__ k1, const float* __restrict__ k2,
                          const float* __restrict__ k3, const float* __restrict__ k4,
                          const float* __restrict__ k5,
                          short* __restrict__ w1, short* __restrict__ w2,
                          short* __restrict__ w3, short* __restrict__ w4,
                          short* __restrict__ w5) {
    const int CINt[5]  = {134, 128, 128, 96, 64};
    const int COUTt[5] = {128, 128, 96, 64, 32};
    const int KCt[5]   = {5, 4, 4, 3, 2};
    const float* srcs[5] = {k1, k2, k3, k4, k5};
    short* dsts[5] = {w1, w2, w3, w4, w5};
    int l = blockIdx.y;
    int CIN = CINt[l], COUT = COUTt[l], KC = KCt[l];
    const float* k = srcs[l];
    short* wt = dsts[l];
    int idx = blockIdx.x * 256 + threadIdx.x;
    int total = 9 * KC * COUT * 32;
    if (idx >= total) return;
    int j = idx & 7;
    int s = (idx >> 3) & 3;
    int rest = idx >> 5;              // (kc*9+tap)*COUT + n
    int n = rest % COUT; rest /= COUT;
    int tap = rest % 9, kc = rest / 9;
    int q = (s - n) & 3;
    int kk = q * 8 + j;
    int ci = kc * 32 + kk;
    float v = (ci < CIN) ? k[(size_t)(tap * CIN + ci) * COUT + n] : 0.f;
    wt[idx] = (short)f2b(v);
}

// 3x3 SAME conv, halo layout [B,130,258,CIN_STR] -> [B,130,258,COUT].
// Block: 512 thr = 8 waves; tile = 4 rows x 64 cols x COUT. Wave = (row r) x
// (n-half h): 64 px x COUT/2 -> acc[4][NT] = 64 f32/lane. With LDS
// A(25,344B) + W-row dbuf(2x3 taps, <=49,152B) = 74.5 KB and <=128 unified
// regs (__launch_bounds__(512,4)) -> 2 blocks/CU: the co-resident block hides
// the A-stage vmcnt drain that was fully exposed before (TLP, not manual
// pipelining). W stays in LDS (L2-resident source), staged per dy-row,
// double-buffered + prefetched one phase ahead -> its drain is free.
// W reads conflict-free via slot=(q+col)&3 baked into the global layout.
// XCD-chunked swizzle: 128 consecutive blocks (= one batch image) per XCD.
template <int KC, int CIN_STR, int COUT, int NT, int LASTC>
__launch_bounds__(512, 4)
__global__ void conv3x3_kernel(const short* __restrict__ in, const short* __restrict__ wt,
                               const float* __restrict__ bias, short* __restrict__ out) {
    __shared__ short ldsA[6 * 66 * 4 * 8];          // 25,344 B
    __shared__ short ldsW[2][3 * COUT * 32];        // 2 x (3*COUT*32*2 B)

    int t = threadIdx.x;
    int lane = t & 63, wid = t >> 6;
    int q = lane >> 4, col = lane & 15;
    int r = wid & 3, h = wid >> 2;                  // wave = out-row r, n-half h
    const int NH = COUT / 2;

    int blk = blockIdx.x;
    blk = (blk & 7) * 128 + (blk >> 3);             // bijective: 1024 % 8 == 0
    int wtile = blk & 3;
    int rest = blk >> 2;
    int htile = rest & 31, b = rest >> 5;
    int w0h = wtile << 6;                           // staged cols w0h .. w0h+65
    int row0 = htile << 2;                          // staged rows row0 .. row0+5

    const short* inbase = in + ((size_t)(b * 130 + row0) * 258 + w0h) * CIN_STR;

    // stage A chunk kc: 1584 granules (r*264 + p*4 + s); slot s holds chunk c=(s-p)&3
    auto stageA = [&](int kc) {
        for (int i = t; i < 1584; i += 512) {
            int rr2 = i / 264, rem = i % 264;
            int p = rem >> 2, s = rem & 3;
            int c = (s - p) & 3;
            if (LASTC == 4 || kc < KC - 1 || c < LASTC) {
                const short* g = inbase + ((size_t)rr2 * 258 + p) * CIN_STR + kc * 32 + c * 8;
                async16(g, ldsA + (size_t)(i & ~63) * 8);
            }
        }
    };
    // stage W phase ph = kc*3+dy (3 taps, identity copy of pre-swizzled layout)
    auto stageW = [&](int ph) {
        const short* wsrc = wt + (size_t)(3 * ph) * COUT * 32;
        short* dst = &ldsW[ph & 1][0];
        for (int i = t; i < COUT * 12; i += 512)
            async16(wsrc + (size_t)i * 8, dst + (size_t)(i & ~63) * 8);
    };

    f32x4 acc[4][NT] = {};

    stageW(0);
    for (int kc = 0; kc < KC; ++kc) {
        stageA(kc);
        __syncthreads();                            // A + current W row landed
#pragma unroll
        for (int dy = 0; dy < 3; ++dy) {
            int ph = kc * 3 + dy;
            if (ph + 1 < 3 * KC) stageW(ph + 1);    // prefetch next W row
            const short* WB = &ldsW[ph & 1][0];
            int ldsrow = r + dy;
#pragma unroll
            for (int dx = 0; dx < 3; ++dx) {
                short8 a[4], bfr[NT];
#pragma unroll
                for (int mt = 0; mt < 4; ++mt) {
                    int p = mt * 16 + col + dx;
                    a[mt] = *(const short8*)(ldsA +
                        (size_t)(((ldsrow * 66 + p) << 2) + ((q + p) & 3)) * 8);
                }
#pragma unroll
                for (int nt = 0; nt < NT; ++nt) {
                    int n = h * NH + nt * 16 + col;
                    bfr[nt] = *(const short8*)(WB +
                        (size_t)((dx * COUT + n) * 4 + ((q + col) & 3)) * 8);
                }
#pragma unroll
                for (int mt = 0; mt < 4; ++mt)
#pragma unroll
                    for (int nt = 0; nt < NT; ++nt)
                        acc[mt][nt] = __builtin_amdgcn_mfma_f32_16x16x32_bf16(
                            a[mt], bfr[nt], acc[mt][nt], 0, 0, 0);
            }
            __syncthreads();   // readers of ldsW[ph&1] done; prefetch drained
        }
    }

    // ---- epilogue: D[m = mt*16 + q*4 + rr][n = h*NH + nt*16 + col] ----
    size_t obase = ((size_t)(b * 130 + row0 + 1 + r) * 258 + (w0h + 1)) * COUT + h * NH;
#pragma unroll
    for (int nt = 0; nt < NT; ++nt) {
        float bv = bias[h * NH + nt * 16 + col];
#pragma unroll
        for (int mt = 0; mt < 4; ++mt) {
#pragma unroll
            for (int rr = 0; rr < 4; ++rr) {
                int m = mt * 16 + q * 4 + rr;
                float v = acc[mt][nt][rr] + bv;
                v = (v >= 0.f) ? v : LEAK * v;
                out[obase + (size_t)m * COUT + nt * 16 + col] = (short)f2b(v);
            }
        }
    }
}

// conv6: 3x3, Cin=32 (halo layout), Cout=1, linear, fp32 out (flat [B,H,W])
__global__ void conv6_kernel(const short* __restrict__ x, const float* __restrict__ k,
                             const float* __restrict__ bias, float* __restrict__ out) {
    __shared__ float wk[288];
    int t = threadIdx.x;
    for (int i = t; i < 288; i += 256) wk[i] = k[i];
    __syncthreads();
    int idx = blockIdx.x * 256 + t;
    int w = idx & 255, h = (idx >> 8) & 127, b = idx >> 15;
    float acc = bias[0];
#pragma unroll
    for (int dy = 0; dy < 3; ++dy) {
#pragma unroll
        for (int dx = 0; dx < 3; ++dx) {
            const short* xp = x + ((size_t)(b * 130 + h + dy) * 258 + (w + dx)) * 32;
            const float* wp = wk + (dy * 3 + dx) * 32;
#pragma unroll
            for (int c8 = 0; c8 < 4; ++c8) {
                short8 v = *(const short8*)(xp + c8 * 8);
#pragma unroll
                for (int j = 0; j < 8; ++j)
                    acc += b2f((unsigned short)v[j]) * wp[c8 * 8 + j];
            }
        }
    }
    out[idx] = acc;
}

extern "C" void kernel_launch(void* const* d_in, const int* in_sizes, int n_in,
                              void* d_out, int out_size, void* d_ws, size_t ws_size,
                              hipStream_t stream) {
    const float* left  = (const float*)d_in[0];
    const float* right = (const float*)d_in[1];
    const float* pd    = (const float*)d_in[2];
    const float* k[6];
    const float* bb[6];
    for (int i = 0; i < 6; ++i) { k[i] = (const float*)d_in[3 + 2 * i]; bb[i] = (const float*)d_in[4 + 2 * i]; }

    char* ws = (char*)d_ws;
    // weights: [0, 1 MiB)
    short* wt1 = (short*)ws;
    short* wt2 = (short*)(ws + 368640);
    short* wt3 = (short*)(ws + 663552);
    short* wt4 = (short*)(ws + 884736);
    short* wt5 = (short*)(ws + 995328);
    // region A @1 MiB: vol(C=144) -> X2(128) -> X4(64); region B: X1(128) -> X3(96) -> X5(32)
    short* vol = (short*)(ws + 1048576);
    short* X1  = (short*)(ws + 1048576 + 77276160);
    short* X2  = vol;
    short* X3  = X1;
    short* X4  = vol;
    short* X5  = X1;

    auto hz = [&](short* buf, int C) {
        int blocks = (8 * 772 * (C >> 3) + 255) / 256;
        halo_zero_one<<<blocks, 256, 0, stream>>>(buf, C);
    };

    prep_kernel<<<4096, 256, 0, stream>>>(left, right, pd, vol);
    wconv_all<<<dim3(720, 5), 256, 0, stream>>>(k[0], k[1], k[2], k[3], k[4],
                                                wt1, wt2, wt3, wt4, wt5);
    hz(vol, 144);
    hz(X1, 128);

    conv3x3_kernel<5, 144, 128, 4, 2><<<1024, 512, 0, stream>>>(vol, wt1, bb[0], X1);
    hz(X2, 128);   // region A: only after conv1 finished reading vol
    conv3x3_kernel<4, 128, 128, 4, 4><<<1024, 512, 0, stream>>>(X1, wt2, bb[1], X2);
    hz(X3, 96);    // region B: only after conv2 finished reading X1
    conv3x3_kernel<4, 128,  96, 3, 4><<<1024, 512, 0, stream>>>(X2, wt3, bb[2], X3);
    hz(X4, 64);    // region A: only after conv3 finished reading X2
    conv3x3_kernel<3,  96,  64, 2, 4><<<1024, 512, 0, stream>>>(X3, wt4, bb[3], X4);
    hz(X5, 32);    // region B: only after conv4 finished reading X3
    conv3x3_kernel<2,  64,  32, 1, 4><<<1024, 512, 0, stream>>>(X4, wt5, bb[4], X5);
    conv6_kernel<<<1024, 256, 0, stream>>>(X5, k[5], bb[5], (float*)d_out);
}

// Round 3
// 775.735 us; speedup vs baseline: 1.0986x; 1.0986x over previous
//
#include <hip/hip_runtime.h>

typedef __attribute__((ext_vector_type(8))) short short8;
typedef __attribute__((ext_vector_type(4))) float f32x4;
typedef __attribute__((ext_vector_type(4))) unsigned short us4;

#define LEAK 0.2f

__device__ __forceinline__ float b2f(unsigned short s) {
    unsigned u = ((unsigned)s) << 16;
    return __builtin_bit_cast(float, u);
}
__device__ __forceinline__ unsigned short f2b(float f) {
    unsigned u = __builtin_bit_cast(unsigned, f);
    u += 0x7fffu + ((u >> 16) & 1u);
    return (unsigned short)(u >> 16);
}

// async 16B global->LDS (direct-to-shared DMA). LDS base wave-uniform; HW adds lane*16.
__device__ __forceinline__ void async16(const short* g, short* l) {
    __builtin_amdgcn_global_load_lds(
        (const __attribute__((address_space(1))) void*)g,
        (__attribute__((address_space(3))) void*)l, 16, 0, 0);
}

// ---------------- prep: upsample / warp / cost volume (LDS-staged, coalesced) ----
// Block = 64 pixels of one row (quarter row). All global I/O is 16B/lane contiguous.
// vol: halo layout [B,130,258,144] bf16; interior pixel (h,w) -> row h+1, col w+1.
// ch 0..127 = left(bf16), 128..132 = costs, 133 = up, 134..143 = 0.
__global__ __launch_bounds__(256)
void prep_kernel(const float* __restrict__ left, const float* __restrict__ right,
                 const float* __restrict__ pd, short* __restrict__ vol) {
    __shared__ __align__(16) float inL[64 * 132];   // [px][128 ch + 4 pad]
    __shared__ __align__(16) float rrow[256];       // right row (b,h)
    __shared__ __align__(16) float pr0[128];        // pd row y0c
    __shared__ __align__(16) float pr1[128];        // pd row y1c
    __shared__ __align__(16) short outT[64 * 144];  // output tile

    int t = threadIdx.x;
    int blk = blockIdx.x;                 // 4096 = b(8) * h(128) * wq(4)
    int wq = blk & 3, h = (blk >> 2) & 127, b = blk >> 9;
    int w0 = wq << 6;

    // row-uniform upsample y terms
    float sy = h * 0.5f - 0.25f;
    float fy0 = floorf(sy);
    float fy = sy - fy0;
    int y0 = (int)fy0;
    int y0c = min(max(y0, 0), 63), y1c = min(max(y0 + 1, 0), 63);

    // ---- phase 1: coalesced loads -> LDS ----
    const float* lp = left + ((size_t)((b * 128 + h) * 256 + w0)) * 128;
#pragma unroll
    for (int k2 = 0; k2 < 8; ++k2) {
        int g = t + k2 * 256;             // granule 0..2047 (16B each)
        int p = g >> 5, j = g & 31;
        float4 v = *(const float4*)(lp + (size_t)g * 4);
        *(float4*)(&inL[p * 132 + j * 4]) = v;
    }
    if (t < 64) {
        *(float4*)(&rrow[t * 4]) =
            *(const float4*)(right + ((size_t)(b * 128 + h)) * 256 + t * 4);
    } else if (t < 96) {
        int i2 = t - 64;
        *(float4*)(&pr0[i2 * 4]) = *(const float4*)(pd + (size_t)(b * 64 + y0c) * 128 + i2 * 4);
    } else if (t < 128) {
        int i2 = t - 96;
        *(float4*)(&pr1[i2 * 4]) = *(const float4*)(pd + (size_t)(b * 64 + y1c) * 128 + i2 * 4);
    }
    __syncthreads();

    // ---- phase 2: 4 threads per pixel ----
    int p = t >> 2, s = t & 3;
    int w = w0 + p;
    const float* src = &inL[p * 132 + s * 32];
    short* odst = &outT[p * 144 + s * 32];
    float sum = 0.f;
#pragma unroll
    for (int i = 0; i < 8; ++i) {
        float f0 = src[i * 4], f1 = src[i * 4 + 1], f2 = src[i * 4 + 2], f3 = src[i * 4 + 3];
        sum += (f0 + f1) + (f2 + f3);
        us4 o;
        o.x = f2b(f0); o.y = f2b(f1); o.z = f2b(f2); o.w = f2b(f3);
        *(us4*)(odst + i * 4) = o;
    }
    sum += __shfl_xor(sum, 1);
    sum += __shfl_xor(sum, 2);
    float mean = sum * (1.f / 128.f);

    float one_fy = 1.f - fy;
#pragma unroll
    for (int tap = s; tap < 5; tap += 4) {   // s=0 -> taps 0,4; s=1,2,3 -> taps 1,2,3
        int jj = w + tap - 2;
        if (jj >= 0 && jj < 256) {
            float sx = jj * 0.5f - 0.25f;
            float fx0 = floorf(sx);
            float fx = sx - fx0;
            int x0 = (int)fx0;
            int x0c = min(max(x0, 0), 127), x1c = min(max(x0 + 1, 0), 127);
            float up = one_fy * ((1.f - fx) * pr0[x0c] + fx * pr0[x1c])
                     + fy     * ((1.f - fx) * pr1[x0c] + fx * pr1[x1c]);
            float cx = (float)jj - up;
            float xf0 = floorf(cx), xf1 = xf0 + 1.f;
            float w0x = xf1 - cx, w1x = cx - xf0;
            int ix0 = (int)fminf(fmaxf(xf0, 0.f), 255.f);
            int ix1 = (int)fminf(fmaxf(xf1, 0.f), 255.f);
            float warped = w0x * rrow[ix0] + w1x * rrow[ix1];
            outT[p * 144 + 128 + tap] = (short)f2b(warped * mean);
            if (tap == 2) outT[p * 144 + 133] = (short)f2b(up);   // jj==w always in-range
        } else {
            outT[p * 144 + 128 + tap] = 0;
        }
    }
    if (s == 0) { outT[p * 144 + 134] = 0; outT[p * 144 + 135] = 0; }
    if (s == 3) {
        us4 z = {};
        *(us4*)(&outT[p * 144 + 136]) = z;
        *(us4*)(&outT[p * 144 + 140]) = z;
    }
    __syncthreads();

    // ---- phase 3: coalesced store (tile is contiguous in halo layout) ----
    short* gdst = vol + ((size_t)(b * 130 + h + 1) * 258 + (w0 + 1)) * 144;
    for (int g = t; g < 1152; g += 256)
        *(short8*)(gdst + g * 8) = *(const short8*)(&outT[g * 8]);
}

// zero the halo ring of ONE buffer (schedule AFTER last reader of aliased layout)
__global__ void halo_zero_one(short* __restrict__ buf, int C) {
    int nchunk = C >> 3;
    int slot = blockIdx.x * 256 + threadIdx.x;
    int total = 8 * 772 * nchunk;
    if (slot >= total) return;
    int chunk = slot % nchunk;
    int pix = slot / nchunk;
    int b = pix / 772, p = pix % 772;
    int row, col;
    if (p < 516) { row = (p < 258) ? 0 : 129; col = (p < 258) ? p : p - 258; }
    else { int q = p - 516; row = 1 + (q >> 1); col = (q & 1) ? 257 : 0; }
    short8 z = {};
    *(short8*)(buf + ((size_t)(b * 130 + row) * 258 + col) * C + chunk * 8) = z;
}

// fp32 HWIO weights -> bf16 swizzled layout, all 5 layers in one launch.
// Layout (shorts): granule g = ((kc*9+tap)*COUT + n)*4 + s, where slot s holds
// k-quarter q = (s - n) & 3; within granule, 8 consecutive k (q*8..q*8+7).
// k zero-padded past CIN. Staged to LDS linearly (identity copy, legal for
// global_load_lds); read with slot=(q+n)&3 -> the A-pattern form 4n+((q+n)&3),
// which round-0 counters show is conflict-free (vs 4n+q at 6 extra cy/read).
__global__ void wconv_all(const float* __restrict__ k1, const float* __restrict__ k2,
                          const float* __restrict__ k3, const float* __restrict__ k4,
                          const float* __restrict__ k5,
                          short* __restrict__ w1, short* __restrict__ w2,
                          short* __restrict__ w3, short* __restrict__ w4,
                          short* __restrict__ w5) {
    const int CINt[5]  = {134, 128, 128, 96, 64};
    const int COUTt[5] = {128, 128, 96, 64, 32};
    const int KCt[5]   = {5, 4, 4, 3, 2};
    const float* srcs[5] = {k1, k2, k3, k4, k5};
    short* dsts[5] = {w1, w2, w3, w4, w5};
    int l = blockIdx.y;
    int CIN = CINt[l], COUT = COUTt[l], KC = KCt[l];
    const float* k = srcs[l];
    short* wt = dsts[l];
    int idx = blockIdx.x * 256 + threadIdx.x;
    int total = 9 * KC * COUT * 32;
    if (idx >= total) return;
    int j = idx & 7;
    int s = (idx >> 3) & 3;
    int rest = idx >> 5;              // (kc*9+tap)*COUT + n
    int n = rest % COUT; rest /= COUT;
    int tap = rest % 9, kc = rest / 9;
    int q = (s - n) & 3;
    int kk = q * 8 + j;
    int ci = kc * 32 + kk;
    float v = (ci < CIN) ? k[(size_t)(tap * CIN + ci) * COUT + n] : 0.f;
    wt[idx] = (short)f2b(v);
}

// 3x3 SAME conv, halo layout [B,130,258,CIN_STR] -> [B,130,258,COUT].
// Round-0 structure (verified fastest): 512 blocks x 512 thr = 8 waves;
// tile M=512 px (4 rows x 128 cols); wave = 64 px x full COUT; acc[4][NT]
// (128 f32 -> AGPRs); __launch_bounds__(512,2) so regs are NOT starved
// (round-2 lesson: (512,4) spilled acc -> +400 MB scratch traffic).
// New vs round 0:
//  * A double-buffered (2x49,920B), prefetched in three 64-aligned parts,
//    one part per dy-phase -> every __syncthreads vmcnt-drain waits on loads
//    that already had a full compute phase in flight (drain free).
//  * W staged per dy-row (3 taps), double-buffered (2x3*COUT*32 shorts),
//    prefetched one phase ahead from L2-resident pre-swizzled global layout.
//  * W reads conflict-free via slot=(q+n)&3 baked into the global layout
//    (kills round-0's 8.85M LDS bank-conflict cycles = 6 cy x every W read).
//  * bijective XCD-chunk swizzle (512%8==0): each XCD owns one batch image.
// LDS total 148,992 B -> 1 block/CU (same occupancy as round 0).
template <int KC, int CIN_STR, int COUT, int NT, int LASTC>
__launch_bounds__(512, 2)
__global__ void conv3x3_kernel(const short* __restrict__ in, const short* __restrict__ wt,
                               const float* __restrict__ bias, short* __restrict__ out) {
    __shared__ short ldsA[2][6 * 130 * 4 * 8];      // 2 x 49,920 B
    __shared__ short ldsW[2][3 * COUT * 32];        // 2 x (3*COUT*32*2 B)

    int t = threadIdx.x;
    int lane = t & 63, wid = t >> 6;
    int q = lane >> 4, col = lane & 15;
    int out_row = wid >> 1, col_off = (wid & 1) << 6;

    int blk = blockIdx.x;
    blk = (blk & 7) * 64 + (blk >> 3);           // 512 % 8 == 0: bijective; 1 image/XCD
    int wtile = blk & 1;
    int rest = blk >> 1;
    int htile = rest & 31, b = rest >> 5;
    int w0h = wtile << 7;                        // staged col range w0h .. w0h+129
    int row0 = htile << 2;                       // staged rows row0 .. row0+5

    const short* inbase = in + ((size_t)(b * 130 + row0) * 258 + w0h) * CIN_STR;

    // stage one 64-aligned part of A chunk skc into buffer d.
    // granule i = r*520 + p*4 + s; slot s holds channel-chunk c = (s-p)&3.
    // parts: [0,1024), [1024,2048), [2048,3120) — starts are multiples of 64
    // so (i & ~63) is the issuing wave's base (required by global_load_lds).
    auto stageA = [&](int skc, int d, int part) {
        short* dst = &ldsA[d][0];
        int lo = (part == 0) ? 0 : (part == 1) ? 1024 : 2048;
        int hi = (part == 0) ? 1024 : (part == 1) ? 2048 : 3120;
        for (int i = lo + t; i < hi; i += 512) {
            int r = i / 520, rem = i % 520;
            int p = rem >> 2, s = rem & 3;
            int c = (s - p) & 3;
            if (LASTC == 4 || skc < KC - 1 || c < LASTC) {
                const short* g = inbase + ((size_t)r * 258 + p) * CIN_STR + skc * 32 + c * 8;
                async16(g, dst + (size_t)(i & ~63) * 8);
            }
        }
    };
    // stage W phase ph = kc*3+dy (3 taps, identity copy of pre-swizzled layout)
    auto stageW = [&](int ph) {
        const short* wsrc = wt + (size_t)(3 * ph) * COUT * 32;
        short* dst = &ldsW[ph & 1][0];
        for (int i = t; i < COUT * 12; i += 512)
            async16(wsrc + (size_t)i * 8, dst + (size_t)(i & ~63) * 8);
    };

    f32x4 acc[4][NT] = {};

    stageW(0);
    stageA(0, 0, 0); stageA(0, 0, 1); stageA(0, 0, 2);
    __syncthreads();

    for (int kc = 0; kc < KC; ++kc) {
        const short* A = &ldsA[kc & 1][0];
#pragma unroll
        for (int dy = 0; dy < 3; ++dy) {
            int ph = kc * 3 + dy;
            // prefetches first: they get the whole phase (~3.7k cy) in flight
            if (ph + 1 < 3 * KC) stageW(ph + 1);
            if (kc + 1 < KC) stageA(kc + 1, (kc + 1) & 1, dy);
            const short* WB = &ldsW[ph & 1][0];
            int ldsrow = out_row + dy;
#pragma unroll
            for (int dx = 0; dx < 3; ++dx) {
                short8 a[4], bfr[NT];
#pragma unroll
                for (int mt = 0; mt < 4; ++mt) {
                    int p = col_off + mt * 16 + col + dx;
                    a[mt] = *(const short8*)(A +
                        (size_t)(((ldsrow * 130 + p) << 2) + ((q + p) & 3)) * 8);
                }
#pragma unroll
                for (int nt = 0; nt < NT; ++nt) {
                    int n = nt * 16 + col;
                    bfr[nt] = *(const short8*)(WB +
                        (size_t)(((dx * COUT + n) << 2) + ((q + n) & 3)) * 8);
                }
#pragma unroll
                for (int mt = 0; mt < 4; ++mt)
#pragma unroll
                    for (int nt = 0; nt < NT; ++nt)
                        acc[mt][nt] = __builtin_amdgcn_mfma_f32_16x16x32_bf16(
                            a[mt], bfr[nt], acc[mt][nt], 0, 0, 0);
            }
            __syncthreads();   // ldsW[ph&1] readers done; prefetched loads drained free
        }
    }

    // ---- epilogue: D[m = mt*16 + q*4 + rr][n = nt*16 + col], leaky-relu, bf16 ----
    size_t obase = ((size_t)(b * 130 + row0 + 1 + out_row) * 258 + (w0h + 1 + col_off)) * COUT;
#pragma unroll
    for (int nt = 0; nt < NT; ++nt) {
        int n = nt * 16 + col;
        float bv = bias[n];
#pragma unroll
        for (int mt = 0; mt < 4; ++mt) {
#pragma unroll
            for (int rr = 0; rr < 4; ++rr) {
                int m = mt * 16 + q * 4 + rr;
                float v = acc[mt][nt][rr] + bv;
                v = (v >= 0.f) ? v : LEAK * v;
                out[obase + (size_t)m * COUT + n] = (short)f2b(v);
            }
        }
    }
}

// conv6: 3x3, Cin=32 (halo layout), Cout=1, linear, fp32 out (flat [B,H,W])
__global__ void conv6_kernel(const short* __restrict__ x, const float* __restrict__ k,
                             const float* __restrict__ bias, float* __restrict__ out) {
    __shared__ float wk[288];
    int t = threadIdx.x;
    for (int i = t; i < 288; i += 256) wk[i] = k[i];
    __syncthreads();
    int idx = blockIdx.x * 256 + t;
    int w = idx & 255, h = (idx >> 8) & 127, b = idx >> 15;
    float acc = bias[0];
#pragma unroll
    for (int dy = 0; dy < 3; ++dy) {
#pragma unroll
        for (int dx = 0; dx < 3; ++dx) {
            const short* xp = x + ((size_t)(b * 130 + h + dy) * 258 + (w + dx)) * 32;
            const float* wp = wk + (dy * 3 + dx) * 32;
#pragma unroll
            for (int c8 = 0; c8 < 4; ++c8) {
                short8 v = *(const short8*)(xp + c8 * 8);
#pragma unroll
                for (int j = 0; j < 8; ++j)
                    acc += b2f((unsigned short)v[j]) * wp[c8 * 8 + j];
            }
        }
    }
    out[idx] = acc;
}

extern "C" void kernel_launch(void* const* d_in, const int* in_sizes, int n_in,
                              void* d_out, int out_size, void* d_ws, size_t ws_size,
                              hipStream_t stream) {
    const float* left  = (const float*)d_in[0];
    const float* right = (const float*)d_in[1];
    const float* pd    = (const float*)d_in[2];
    const float* k[6];
    const float* bb[6];
    for (int i = 0; i < 6; ++i) { k[i] = (const float*)d_in[3 + 2 * i]; bb[i] = (const float*)d_in[4 + 2 * i]; }

    char* ws = (char*)d_ws;
    // weights: [0, 1 MiB)
    short* wt1 = (short*)ws;
    short* wt2 = (short*)(ws + 368640);
    short* wt3 = (short*)(ws + 663552);
    short* wt4 = (short*)(ws + 884736);
    short* wt5 = (short*)(ws + 995328);
    // region A @1 MiB: vol(C=144) -> X2(128) -> X4(64); region B: X1(128) -> X3(96) -> X5(32)
    short* vol = (short*)(ws + 1048576);
    short* X1  = (short*)(ws + 1048576 + 77276160);
    short* X2  = vol;
    short* X3  = X1;
    short* X4  = vol;
    short* X5  = X1;

    auto hz = [&](short* buf, int C) {
        int blocks = (8 * 772 * (C >> 3) + 255) / 256;
        halo_zero_one<<<blocks, 256, 0, stream>>>(buf, C);
    };

    prep_kernel<<<4096, 256, 0, stream>>>(left, right, pd, vol);
    wconv_all<<<dim3(720, 5), 256, 0, stream>>>(k[0], k[1], k[2], k[3], k[4],
                                                wt1, wt2, wt3, wt4, wt5);
    hz(vol, 144);
    hz(X1, 128);

    conv3x3_kernel<5, 144, 128, 8, 2><<<512, 512, 0, stream>>>(vol, wt1, bb[0], X1);
    hz(X2, 128);   // region A: only after conv1 finished reading vol
    conv3x3_kernel<4, 128, 128, 8, 4><<<512, 512, 0, stream>>>(X1, wt2, bb[1], X2);
    hz(X3, 96);    // region B: only after conv2 finished reading X1
    conv3x3_kernel<4, 128,  96, 6, 4><<<512, 512, 0, stream>>>(X2, wt3, bb[2], X3);
    hz(X4, 64);    // region A: only after conv3 finished reading X2
    conv3x3_kernel<3,  96,  64, 4, 4><<<512, 512, 0, stream>>>(X3, wt4, bb[3], X4);
    hz(X5, 32);    // region B: only after conv4 finished reading X3
    conv3x3_kernel<2,  64,  32, 2, 4><<<512, 512, 0, stream>>>(X4, wt5, bb[4], X5);
    conv6_kernel<<<1024, 256, 0, stream>>>(X5, k[5], bb[5], (float*)d_out);
}

// Round 4
// 650.625 us; speedup vs baseline: 1.3099x; 1.1923x over previous
//
#include <hip/hip_runtime.h>

typedef __attribute__((ext_vector_type(8))) short short8;
typedef __attribute__((ext_vector_type(4))) float f32x4;
typedef __attribute__((ext_vector_type(4))) unsigned short us4;

#define LEAK 0.2f

__device__ __forceinline__ float b2f(unsigned short s) {
    unsigned u = ((unsigned)s) << 16;
    return __builtin_bit_cast(float, u);
}
__device__ __forceinline__ unsigned short f2b(float f) {
    unsigned u = __builtin_bit_cast(unsigned, f);
    u += 0x7fffu + ((u >> 16) & 1u);
    return (unsigned short)(u >> 16);
}

// async 16B global->LDS (direct-to-shared DMA). LDS base wave-uniform; HW adds lane*16.
__device__ __forceinline__ void async16(const short* g, short* l) {
    __builtin_amdgcn_global_load_lds(
        (const __attribute__((address_space(1))) void*)g,
        (__attribute__((address_space(3))) void*)l, 16, 0, 0);
}

// ---------------- prep: upsample / warp / cost volume (LDS-staged, coalesced) ----
// Block = 64 pixels of one row (quarter row). All global I/O is 16B/lane contiguous.
// vol: halo layout [B,130,258,144] bf16; interior pixel (h,w) -> row h+1, col w+1.
// ch 0..127 = left(bf16), 128..132 = costs, 133 = up, 134..143 = 0.
__global__ __launch_bounds__(256)
void prep_kernel(const float* __restrict__ left, const float* __restrict__ right,
                 const float* __restrict__ pd, short* __restrict__ vol) {
    __shared__ __align__(16) float inL[64 * 132];   // [px][128 ch + 4 pad]
    __shared__ __align__(16) float rrow[256];       // right row (b,h)
    __shared__ __align__(16) float pr0[128];        // pd row y0c
    __shared__ __align__(16) float pr1[128];        // pd row y1c
    __shared__ __align__(16) short outT[64 * 144];  // output tile

    int t = threadIdx.x;
    int blk = blockIdx.x;                 // 4096 = b(8) * h(128) * wq(4)
    int wq = blk & 3, h = (blk >> 2) & 127, b = blk >> 9;
    int w0 = wq << 6;

    // row-uniform upsample y terms
    float sy = h * 0.5f - 0.25f;
    float fy0 = floorf(sy);
    float fy = sy - fy0;
    int y0 = (int)fy0;
    int y0c = min(max(y0, 0), 63), y1c = min(max(y0 + 1, 0), 63);

    // ---- phase 1: coalesced loads -> LDS ----
    const float* lp = left + ((size_t)((b * 128 + h) * 256 + w0)) * 128;
#pragma unroll
    for (int k2 = 0; k2 < 8; ++k2) {
        int g = t + k2 * 256;             // granule 0..2047 (16B each)
        int p = g >> 5, j = g & 31;
        float4 v = *(const float4*)(lp + (size_t)g * 4);
        *(float4*)(&inL[p * 132 + j * 4]) = v;
    }
    if (t < 64) {
        *(float4*)(&rrow[t * 4]) =
            *(const float4*)(right + ((size_t)(b * 128 + h)) * 256 + t * 4);
    } else if (t < 96) {
        int i2 = t - 64;
        *(float4*)(&pr0[i2 * 4]) = *(const float4*)(pd + (size_t)(b * 64 + y0c) * 128 + i2 * 4);
    } else if (t < 128) {
        int i2 = t - 96;
        *(float4*)(&pr1[i2 * 4]) = *(const float4*)(pd + (size_t)(b * 64 + y1c) * 128 + i2 * 4);
    }
    __syncthreads();

    // ---- phase 2: 4 threads per pixel ----
    int p = t >> 2, s = t & 3;
    int w = w0 + p;
    const float* src = &inL[p * 132 + s * 32];
    short* odst = &outT[p * 144 + s * 32];
    float sum = 0.f;
#pragma unroll
    for (int i = 0; i < 8; ++i) {
        float f0 = src[i * 4], f1 = src[i * 4 + 1], f2 = src[i * 4 + 2], f3 = src[i * 4 + 3];
        sum += (f0 + f1) + (f2 + f3);
        us4 o;
        o.x = f2b(f0); o.y = f2b(f1); o.z = f2b(f2); o.w = f2b(f3);
        *(us4*)(odst + i * 4) = o;
    }
    sum += __shfl_xor(sum, 1);
    sum += __shfl_xor(sum, 2);
    float mean = sum * (1.f / 128.f);

    float one_fy = 1.f - fy;
#pragma unroll
    for (int tap = s; tap < 5; tap += 4) {   // s=0 -> taps 0,4; s=1,2,3 -> taps 1,2,3
        int jj = w + tap - 2;
        if (jj >= 0 && jj < 256) {
            float sx = jj * 0.5f - 0.25f;
            float fx0 = floorf(sx);
            float fx = sx - fx0;
            int x0 = (int)fx0;
            int x0c = min(max(x0, 0), 127), x1c = min(max(x0 + 1, 0), 127);
            float up = one_fy * ((1.f - fx) * pr0[x0c] + fx * pr0[x1c])
                     + fy     * ((1.f - fx) * pr1[x0c] + fx * pr1[x1c]);
            float cx = (float)jj - up;
            float xf0 = floorf(cx), xf1 = xf0 + 1.f;
            float w0x = xf1 - cx, w1x = cx - xf0;
            int ix0 = (int)fminf(fmaxf(xf0, 0.f), 255.f);
            int ix1 = (int)fminf(fmaxf(xf1, 0.f), 255.f);
            float warped = w0x * rrow[ix0] + w1x * rrow[ix1];
            outT[p * 144 + 128 + tap] = (short)f2b(warped * mean);
            if (tap == 2) outT[p * 144 + 133] = (short)f2b(up);   // jj==w always in-range
        } else {
            outT[p * 144 + 128 + tap] = 0;
        }
    }
    if (s == 0) { outT[p * 144 + 134] = 0; outT[p * 144 + 135] = 0; }
    if (s == 3) {
        us4 z = {};
        *(us4*)(&outT[p * 144 + 136]) = z;
        *(us4*)(&outT[p * 144 + 140]) = z;
    }
    __syncthreads();

    // ---- phase 3: coalesced store (tile is contiguous in halo layout) ----
    short* gdst = vol + ((size_t)(b * 130 + h + 1) * 258 + (w0 + 1)) * 144;
    for (int g = t; g < 1152; g += 256)
        *(short8*)(gdst + g * 8) = *(const short8*)(&outT[g * 8]);
}

// zero the halo ring of ONE buffer (schedule AFTER last reader of aliased layout)
__global__ void halo_zero_one(short* __restrict__ buf, int C) {
    int nchunk = C >> 3;
    int slot = blockIdx.x * 256 + threadIdx.x;
    int total = 8 * 772 * nchunk;
    if (slot >= total) return;
    int chunk = slot % nchunk;
    int pix = slot / nchunk;
    int b = pix / 772, p = pix % 772;
    int row, col;
    if (p < 516) { row = (p < 258) ? 0 : 129; col = (p < 258) ? p : p - 258; }
    else { int q = p - 516; row = 1 + (q >> 1); col = (q & 1) ? 257 : 0; }
    short8 z = {};
    *(short8*)(buf + ((size_t)(b * 130 + row) * 258 + col) * C + chunk * 8) = z;
}

// fp32 HWIO weights -> bf16 swizzled layout, all 5 layers in one launch.
// Layout (shorts): granule g = ((kc*9+tap)*COUT + n)*4 + s, where slot s holds
// k-quarter q = (s - (n>>1)) & 3; within granule, 8 consecutive k (q*8..q*8+7).
// k zero-padded past CIN. Staged to LDS as identity copy (legal for
// global_load_lds); read with slot=(q+(n>>1))&3.
// WHY >>1: LDS serves a wave64 ds_read_b128 in quarter-wave phases of 16 lanes
// with q CONSTANT inside a phase; granule%8 = 4*(n&1) + slot must walk all 8
// bank groups as col=n&15 varies. slot=(q+(n>>1))&3 does (proof: n mod 8 ->
// {0,4,1,5,2,6,3,7}); slot=(q+n)&3 does NOT (4 groups, 4-way conflict) --
// measured: round-1's (p>>1) A-swizzle = 0 conflicts, (q+p)&3 = 8.85M.
__global__ void wconv_all(const float* __restrict__ k1, const float* __restrict__ k2,
                          const float* __restrict__ k3, const float* __restrict__ k4,
                          const float* __restrict__ k5,
                          short* __restrict__ w1, short* __restrict__ w2,
                          short* __restrict__ w3, short* __restrict__ w4,
                          short* __restrict__ w5) {
    const int CINt[5]  = {134, 128, 128, 96, 64};
    const int COUTt[5] = {128, 128, 96, 64, 32};
    const int KCt[5]   = {5, 4, 4, 3, 2};
    const float* srcs[5] = {k1, k2, k3, k4, k5};
    short* dsts[5] = {w1, w2, w3, w4, w5};
    int l = blockIdx.y;
    int CIN = CINt[l], COUT = COUTt[l], KC = KCt[l];
    const float* k = srcs[l];
    short* wt = dsts[l];
    int idx = blockIdx.x * 256 + threadIdx.x;
    int total = 9 * KC * COUT * 32;
    if (idx >= total) return;
    int j = idx & 7;
    int s = (idx >> 3) & 3;
    int rest = idx >> 5;              // (kc*9+tap)*COUT + n
    int n = rest % COUT; rest /= COUT;
    int tap = rest % 9, kc = rest / 9;
    int q = (s - (n >> 1)) & 3;
    int kk = q * 8 + j;
    int ci = kc * 32 + kk;
    float v = (ci < CIN) ? k[(size_t)(tap * CIN + ci) * COUT + n] : 0.f;
    wt[idx] = (short)f2b(v);
}

// 3x3 SAME conv, halo layout [B,130,258,CIN_STR] -> [B,130,258,COUT].
// EXACT round-0 structure (verified fastest: 624 us net, 120 us/dispatch):
// 512 blocks x 512 thr = 8 waves; tile M=512 px (4 rows x 128 cols); wave =
// 64 px x full COUT; acc[4][NT] (AGPRs); single-buffered A; full-kc W stage;
// __launch_bounds__(512,2). Rounds 1-3 proved: W-from-global thrashes L1
// (r1), reg-starving spills (r2), deep prefetch machinery spills (r3).
// ONLY change vs round 0: phase-correct >>1 slot swizzles on A and W
// (see wconv_all comment) to kill the measured 8.85M LDS conflict cycles.
template <int KC, int CIN_STR, int COUT, int NT, int LASTC>
__launch_bounds__(512, 2)
__global__ void conv3x3_kernel(const short* __restrict__ in, const short* __restrict__ wt,
                               const float* __restrict__ bias, short* __restrict__ out) {
    __shared__ short ldsA[6 * 130 * 4 * 8];      // 49,920 B
    __shared__ short ldsW[9 * COUT * 32];        // COUT=128: 73,728 B
    const int WSLOTS = 9 * COUT * 4;             // 16B granules in the W slice
    const int WSTRIDE = 9 * COUT * 32;           // shorts per kc slice

    int t = threadIdx.x;
    int lane = t & 63, wid = t >> 6;
    int q = lane >> 4, col = lane & 15;
    int out_row = wid >> 1, col_off = (wid & 1) << 6;

    int wtile = blockIdx.x & 1;
    int rest = blockIdx.x >> 1;
    int htile = rest & 31, b = rest >> 5;
    int w0h = wtile << 7;                        // staged col range w0h .. w0h+129
    int row0 = htile << 2;                       // staged rows row0 .. row0+5

    const short* inbase = in + ((size_t)(b * 130 + row0) * 258 + w0h) * CIN_STR;

    f32x4 acc[4][NT] = {};

    for (int kc = 0; kc < KC; ++kc) {
        // ---- stage A: 3120 granules (r*520 + p*4 + s), chunk c=(s-(p>>1))&3 ----
        for (int i = t; i < 3120; i += 512) {
            int r = i / 520, rem = i % 520;
            int p = rem >> 2, s = rem & 3;
            int c = (s - (p >> 1)) & 3;
            if (LASTC == 4 || kc < KC - 1 || c < LASTC) {
                const short* g = inbase + ((size_t)r * 258 + p) * CIN_STR + kc * 32 + c * 8;
                async16(g, ldsA + (size_t)(i & ~63) * 8);
            }
        }
        // ---- stage W: identity copy of the kc slice (pre-swizzled layout) ----
        {
            const short* wsrc = wt + (size_t)kc * WSTRIDE;
            for (int i = t; i < WSLOTS; i += 512)
                async16(wsrc + (size_t)i * 8, ldsW + (size_t)(i & ~63) * 8);
        }
        __syncthreads();

#pragma unroll
        for (int dy = 0; dy < 3; ++dy) {
#pragma unroll
            for (int dx = 0; dx < 3; ++dx) {
                int ldsrow = out_row + dy;
                short8 a[4], bfr[NT];
#pragma unroll
                for (int mt = 0; mt < 4; ++mt) {
                    int p = col_off + mt * 16 + col + dx;
                    a[mt] = *(const short8*)(ldsA +
                        (size_t)(((ldsrow * 130 + p) << 2) + ((q + (p >> 1)) & 3)) * 8);
                }
                const short* wp = ldsW + (size_t)(dy * 3 + dx) * COUT * 32;
#pragma unroll
                for (int nt = 0; nt < NT; ++nt) {
                    int n = nt * 16 + col;
                    bfr[nt] = *(const short8*)(wp +
                        (size_t)((n << 2) + ((q + (n >> 1)) & 3)) * 8);
                }
#pragma unroll
                for (int mt = 0; mt < 4; ++mt)
#pragma unroll
                    for (int nt = 0; nt < NT; ++nt)
                        acc[mt][nt] = __builtin_amdgcn_mfma_f32_16x16x32_bf16(
                            a[mt], bfr[nt], acc[mt][nt], 0, 0, 0);
            }
        }
        __syncthreads();
    }

    // ---- epilogue: D[m = mt*16 + q*4 + rr][n = nt*16 + col], leaky-relu, bf16 ----
    size_t obase = ((size_t)(b * 130 + row0 + 1 + out_row) * 258 + (w0h + 1 + col_off)) * COUT;
#pragma unroll
    for (int nt = 0; nt < NT; ++nt) {
        int n = nt * 16 + col;
        float bv = bias[n];
#pragma unroll
        for (int mt = 0; mt < 4; ++mt) {
#pragma unroll
            for (int rr = 0; rr < 4; ++rr) {
                int m = mt * 16 + q * 4 + rr;
                float v = acc[mt][nt][rr] + bv;
                v = (v >= 0.f) ? v : LEAK * v;
                out[obase + (size_t)m * COUT + n] = (short)f2b(v);
            }
        }
    }
}

// conv6: 3x3, Cin=32 (halo layout), Cout=1, linear, fp32 out (flat [B,H,W])
__global__ void conv6_kernel(const short* __restrict__ x, const float* __restrict__ k,
                             const float* __restrict__ bias, float* __restrict__ out) {
    __shared__ float wk[288];
    int t = threadIdx.x;
    for (int i = t; i < 288; i += 256) wk[i] = k[i];
    __syncthreads();
    int idx = blockIdx.x * 256 + t;
    int w = idx & 255, h = (idx >> 8) & 127, b = idx >> 15;
    float acc = bias[0];
#pragma unroll
    for (int dy = 0; dy < 3; ++dy) {
#pragma unroll
        for (int dx = 0; dx < 3; ++dx) {
            const short* xp = x + ((size_t)(b * 130 + h + dy) * 258 + (w + dx)) * 32;
            const float* wp = wk + (dy * 3 + dx) * 32;
#pragma unroll
            for (int c8 = 0; c8 < 4; ++c8) {
                short8 v = *(const short8*)(xp + c8 * 8);
#pragma unroll
                for (int j = 0; j < 8; ++j)
                    acc += b2f((unsigned short)v[j]) * wp[c8 * 8 + j];
            }
        }
    }
    out[idx] = acc;
}

extern "C" void kernel_launch(void* const* d_in, const int* in_sizes, int n_in,
                              void* d_out, int out_size, void* d_ws, size_t ws_size,
                              hipStream_t stream) {
    const float* left  = (const float*)d_in[0];
    const float* right = (const float*)d_in[1];
    const float* pd    = (const float*)d_in[2];
    const float* k[6];
    const float* bb[6];
    for (int i = 0; i < 6; ++i) { k[i] = (const float*)d_in[3 + 2 * i]; bb[i] = (const float*)d_in[4 + 2 * i]; }

    char* ws = (char*)d_ws;
    // weights: [0, 1 MiB)
    short* wt1 = (short*)ws;
    short* wt2 = (short*)(ws + 368640);
    short* wt3 = (short*)(ws + 663552);
    short* wt4 = (short*)(ws + 884736);
    short* wt5 = (short*)(ws + 995328);
    // region A @1 MiB: vol(C=144) -> X2(128) -> X4(64); region B: X1(128) -> X3(96) -> X5(32)
    short* vol = (short*)(ws + 1048576);
    short* X1  = (short*)(ws + 1048576 + 77276160);
    short* X2  = vol;
    short* X3  = X1;
    short* X4  = vol;
    short* X5  = X1;

    auto hz = [&](short* buf, int C) {
        int blocks = (8 * 772 * (C >> 3) + 255) / 256;
        halo_zero_one<<<blocks, 256, 0, stream>>>(buf, C);
    };

    prep_kernel<<<4096, 256, 0, stream>>>(left, right, pd, vol);
    wconv_all<<<dim3(720, 5), 256, 0, stream>>>(k[0], k[1], k[2], k[3], k[4],
                                                wt1, wt2, wt3, wt4, wt5);
    hz(vol, 144);
    hz(X1, 128);

    conv3x3_kernel<5, 144, 128, 8, 2><<<512, 512, 0, stream>>>(vol, wt1, bb[0], X1);
    hz(X2, 128);   // region A: only after conv1 finished reading vol
    conv3x3_kernel<4, 128, 128, 8, 4><<<512, 512, 0, stream>>>(X1, wt2, bb[1], X2);
    hz(X3, 96);    // region B: only after conv2 finished reading X1
    conv3x3_kernel<4, 128,  96, 6, 4><<<512, 512, 0, stream>>>(X2, wt3, bb[2], X3);
    hz(X4, 64);    // region A: only after conv3 finished reading X2
    conv3x3_kernel<3,  96,  64, 4, 4><<<512, 512, 0, stream>>>(X3, wt4, bb[3], X4);
    hz(X5, 32);    // region B: only after conv4 finished reading X3
    conv3x3_kernel<2,  64,  32, 2, 4><<<512, 512, 0, stream>>>(X4, wt5, bb[4], X5);
    conv6_kernel<<<1024, 256, 0, stream>>>(X5, k[5], bb[5], (float*)d_out);
}

// Round 5
// 604.808 us; speedup vs baseline: 1.4091x; 1.0758x over previous
//
#include <hip/hip_runtime.h>

typedef __attribute__((ext_vector_type(8))) short short8;
typedef __attribute__((ext_vector_type(4))) float f32x4;
typedef __attribute__((ext_vector_type(4))) unsigned short us4;

#define LEAK 0.2f

__device__ __forceinline__ float b2f(unsigned short s) {
    unsigned u = ((unsigned)s) << 16;
    return __builtin_bit_cast(float, u);
}
__device__ __forceinline__ unsigned short f2b(float f) {
    unsigned u = __builtin_bit_cast(unsigned, f);
    u += 0x7fffu + ((u >> 16) & 1u);
    return (unsigned short)(u >> 16);
}

// async 16B global->LDS (direct-to-shared DMA). LDS base wave-uniform; HW adds lane*16.
__device__ __forceinline__ void async16(const short* g, short* l) {
    __builtin_amdgcn_global_load_lds(
        (const __attribute__((address_space(1))) void*)g,
        (__attribute__((address_space(3))) void*)l, 16, 0, 0);
}

// ---------------- prep: upsample / warp / cost volume (LDS-staged, coalesced) ----
// Block = 64 pixels of one row (quarter row). All global I/O is 16B/lane contiguous.
// vol: halo layout [B,130,258,144] bf16; interior pixel (h,w) -> row h+1, col w+1.
// ch 0..127 = left(bf16), 128..132 = costs, 133 = up, 134..143 = 0.
__global__ __launch_bounds__(256)
void prep_kernel(const float* __restrict__ left, const float* __restrict__ right,
                 const float* __restrict__ pd, short* __restrict__ vol) {
    __shared__ __align__(16) float inL[64 * 132];   // [px][128 ch + 4 pad]
    __shared__ __align__(16) float rrow[256];       // right row (b,h)
    __shared__ __align__(16) float pr0[128];        // pd row y0c
    __shared__ __align__(16) float pr1[128];        // pd row y1c
    __shared__ __align__(16) short outT[64 * 144];  // output tile

    int t = threadIdx.x;
    int blk = blockIdx.x;                 // 4096 = b(8) * h(128) * wq(4)
    int wq = blk & 3, h = (blk >> 2) & 127, b = blk >> 9;
    int w0 = wq << 6;

    // row-uniform upsample y terms
    float sy = h * 0.5f - 0.25f;
    float fy0 = floorf(sy);
    float fy = sy - fy0;
    int y0 = (int)fy0;
    int y0c = min(max(y0, 0), 63), y1c = min(max(y0 + 1, 0), 63);

    // ---- phase 1: coalesced loads -> LDS ----
    const float* lp = left + ((size_t)((b * 128 + h) * 256 + w0)) * 128;
#pragma unroll
    for (int k2 = 0; k2 < 8; ++k2) {
        int g = t + k2 * 256;             // granule 0..2047 (16B each)
        int p = g >> 5, j = g & 31;
        float4 v = *(const float4*)(lp + (size_t)g * 4);
        *(float4*)(&inL[p * 132 + j * 4]) = v;
    }
    if (t < 64) {
        *(float4*)(&rrow[t * 4]) =
            *(const float4*)(right + ((size_t)(b * 128 + h)) * 256 + t * 4);
    } else if (t < 96) {
        int i2 = t - 64;
        *(float4*)(&pr0[i2 * 4]) = *(const float4*)(pd + (size_t)(b * 64 + y0c) * 128 + i2 * 4);
    } else if (t < 128) {
        int i2 = t - 96;
        *(float4*)(&pr1[i2 * 4]) = *(const float4*)(pd + (size_t)(b * 64 + y1c) * 128 + i2 * 4);
    }
    __syncthreads();

    // ---- phase 2: 4 threads per pixel ----
    int p = t >> 2, s = t & 3;
    int w = w0 + p;
    const float* src = &inL[p * 132 + s * 32];
    short* odst = &outT[p * 144 + s * 32];
    float sum = 0.f;
#pragma unroll
    for (int i = 0; i < 8; ++i) {
        float f0 = src[i * 4], f1 = src[i * 4 + 1], f2 = src[i * 4 + 2], f3 = src[i * 4 + 3];
        sum += (f0 + f1) + (f2 + f3);
        us4 o;
        o.x = f2b(f0); o.y = f2b(f1); o.z = f2b(f2); o.w = f2b(f3);
        *(us4*)(odst + i * 4) = o;
    }
    sum += __shfl_xor(sum, 1);
    sum += __shfl_xor(sum, 2);
    float mean = sum * (1.f / 128.f);

    float one_fy = 1.f - fy;
#pragma unroll
    for (int tap = s; tap < 5; tap += 4) {   // s=0 -> taps 0,4; s=1,2,3 -> taps 1,2,3
        int jj = w + tap - 2;
        if (jj >= 0 && jj < 256) {
            float sx = jj * 0.5f - 0.25f;
            float fx0 = floorf(sx);
            float fx = sx - fx0;
            int x0 = (int)fx0;
            int x0c = min(max(x0, 0), 127), x1c = min(max(x0 + 1, 0), 127);
            float up = one_fy * ((1.f - fx) * pr0[x0c] + fx * pr0[x1c])
                     + fy     * ((1.f - fx) * pr1[x0c] + fx * pr1[x1c]);
            float cx = (float)jj - up;
            float xf0 = floorf(cx), xf1 = xf0 + 1.f;
            float w0x = xf1 - cx, w1x = cx - xf0;
            int ix0 = (int)fminf(fmaxf(xf0, 0.f), 255.f);
            int ix1 = (int)fminf(fmaxf(xf1, 0.f), 255.f);
            float warped = w0x * rrow[ix0] + w1x * rrow[ix1];
            outT[p * 144 + 128 + tap] = (short)f2b(warped * mean);
            if (tap == 2) outT[p * 144 + 133] = (short)f2b(up);   // jj==w always in-range
        } else {
            outT[p * 144 + 128 + tap] = 0;
        }
    }
    if (s == 0) { outT[p * 144 + 134] = 0; outT[p * 144 + 135] = 0; }
    if (s == 3) {
        us4 z = {};
        *(us4*)(&outT[p * 144 + 136]) = z;
        *(us4*)(&outT[p * 144 + 140]) = z;
    }
    __syncthreads();

    // ---- phase 3: coalesced store (tile is contiguous in halo layout) ----
    short* gdst = vol + ((size_t)(b * 130 + h + 1) * 258 + (w0 + 1)) * 144;
    for (int g = t; g < 1152; g += 256)
        *(short8*)(gdst + g * 8) = *(const short8*)(&outT[g * 8]);
}

// zero the halo ring of ONE buffer (schedule AFTER last reader of aliased layout)
__global__ void halo_zero_one(short* __restrict__ buf, int C) {
    int nchunk = C >> 3;
    int slot = blockIdx.x * 256 + threadIdx.x;
    int total = 8 * 772 * nchunk;
    if (slot >= total) return;
    int chunk = slot % nchunk;
    int pix = slot / nchunk;
    int b = pix / 772, p = pix % 772;
    int row, col;
    if (p < 516) { row = (p < 258) ? 0 : 129; col = (p < 258) ? p : p - 258; }
    else { int q = p - 516; row = 1 + (q >> 1); col = (q & 1) ? 257 : 0; }
    short8 z = {};
    *(short8*)(buf + ((size_t)(b * 130 + row) * 258 + col) * C + chunk * 8) = z;
}

// fp32 HWIO weights -> bf16 swizzled layout, all 5 layers in one launch.
// Layout (shorts): granule g = ((kc*9+tap)*COUT + n)*4 + s, where slot s holds
// k-quarter q = (s - (n>>1)) & 3; within granule, 8 consecutive k (q*8..q*8+7).
// k zero-padded past CIN. Staged to LDS as identity copy (legal for
// global_load_lds); read with slot=(q+(n>>1))&3.
// WHY >>1: LDS serves a wave64 ds_read_b128 in quarter-wave phases of 16 lanes
// with q CONSTANT inside a phase; granule%8 = 4*(n&1) + slot must walk all 8
// bank groups as col=n&15 varies. slot=(q+(n>>1))&3 does; slot=(q+n)&3 does
// NOT (4 groups, 4-way conflict) -- verified round 4: conflicts 8.85M -> 0.
__global__ void wconv_all(const float* __restrict__ k1, const float* __restrict__ k2,
                          const float* __restrict__ k3, const float* __restrict__ k4,
                          const float* __restrict__ k5,
                          short* __restrict__ w1, short* __restrict__ w2,
                          short* __restrict__ w3, short* __restrict__ w4,
                          short* __restrict__ w5) {
    const int CINt[5]  = {134, 128, 128, 96, 64};
    const int COUTt[5] = {128, 128, 96, 64, 32};
    const int KCt[5]   = {5, 4, 4, 3, 2};
    const float* srcs[5] = {k1, k2, k3, k4, k5};
    short* dsts[5] = {w1, w2, w3, w4, w5};
    int l = blockIdx.y;
    int CIN = CINt[l], COUT = COUTt[l], KC = KCt[l];
    const float* k = srcs[l];
    short* wt = dsts[l];
    int idx = blockIdx.x * 256 + threadIdx.x;
    int total = 9 * KC * COUT * 32;
    if (idx >= total) return;
    int j = idx & 7;
    int s = (idx >> 3) & 3;
    int rest = idx >> 5;              // (kc*9+tap)*COUT + n
    int n = rest % COUT; rest /= COUT;
    int tap = rest % 9, kc = rest / 9;
    int q = (s - (n >> 1)) & 3;
    int kk = q * 8 + j;
    int ci = kc * 32 + kk;
    float v = (ci < CIN) ? k[(size_t)(tap * CIN + ci) * COUT + n] : 0.f;
    wt[idx] = (short)f2b(v);
}

// 3x3 SAME conv, halo layout [B,130,258,CIN_STR] -> [B,130,258,COUT].
// Round-4 verified core (0 bank conflicts, 116 VGPR) retiled 4x128 -> 8x64
// rows x cols so that A fits DOUBLE-buffered next to the full-kc W slice:
//   ldsA 2 x 42,240 B + ldsW <= 73,728 B = 158,208 B <= 160 KiB.
// Pipeline per kc (the round-4 counters showed ~17k cy of the 35.4k cy/kc was
// exposed A-stage wait): issue stageA(kc+1) at the TOP of kc, run all 9 taps
// with NO intervening barrier (~18k cy), then __syncthreads -- its vmcnt(0)
// drain is free because the prefetch had the whole compute phase in flight.
// W (L2-resident, ~1.3k cy) is re-staged single-buffered between two barriers.
// Retile also halves the vertical halo: A fetch/kc 49.9 KB -> 42.2 KB.
template <int KC, int CIN_STR, int COUT, int NT, int LASTC>
__launch_bounds__(512, 2)
__global__ void conv3x3_kernel(const short* __restrict__ in, const short* __restrict__ wt,
                               const float* __restrict__ bias, short* __restrict__ out) {
    __shared__ short ldsA[2][10 * 66 * 4 * 8];   // 2 x 42,240 B
    __shared__ short ldsW[9 * COUT * 32];        // COUT=128: 73,728 B
    const int WSLOTS = 9 * COUT * 4;             // 16B granules in the W slice
    const int WSTRIDE = 9 * COUT * 32;           // shorts per kc slice

    int t = threadIdx.x;
    int lane = t & 63, wid = t >> 6;
    int q = lane >> 4, col = lane & 15;
    int out_row = wid;                           // wave = 1 out row x 64 cols

    int wtile = blockIdx.x & 3;
    int rest = blockIdx.x >> 2;
    int htile = rest & 15, b = rest >> 4;
    int w0h = wtile << 6;                        // staged col range w0h .. w0h+65
    int row0 = htile << 3;                       // staged rows row0 .. row0+9

    const short* inbase = in + ((size_t)(b * 130 + row0) * 258 + w0h) * CIN_STR;

    // stage A chunk kc into buffer d: 2640 granules (r*264 + p*4 + s),
    // slot s holds channel-chunk c = (s-(p>>1))&3 (phase-correct swizzle).
    auto stageA = [&](int kc, int d) {
        short* dst = &ldsA[d][0];
        for (int i = t; i < 2640; i += 512) {
            int r = i / 264, rem = i % 264;
            int p = rem >> 2, s = rem & 3;
            int c = (s - (p >> 1)) & 3;
            if (LASTC == 4 || kc < KC - 1 || c < LASTC) {
                const short* g = inbase + ((size_t)r * 258 + p) * CIN_STR + kc * 32 + c * 8;
                async16(g, dst + (size_t)(i & ~63) * 8);
            }
        }
    };
    auto stageW = [&](int kc) {
        const short* wsrc = wt + (size_t)kc * WSTRIDE;
        for (int i = t; i < WSLOTS; i += 512)
            async16(wsrc + (size_t)i * 8, ldsW + (size_t)(i & ~63) * 8);
    };

    f32x4 acc[4][NT] = {};

    stageW(0);
    stageA(0, 0);
    __syncthreads();

    for (int kc = 0; kc < KC; ++kc) {
        // prefetch next A chunk; it has the whole compute phase to land
        if (kc + 1 < KC) stageA(kc + 1, (kc + 1) & 1);
        const short* A = &ldsA[kc & 1][0];

#pragma unroll
        for (int dy = 0; dy < 3; ++dy) {
            int ldsrow = out_row + dy;
#pragma unroll
            for (int dx = 0; dx < 3; ++dx) {
                short8 a[4], bfr[NT];
#pragma unroll
                for (int mt = 0; mt < 4; ++mt) {
                    int p = mt * 16 + col + dx;
                    a[mt] = *(const short8*)(A +
                        (size_t)(((ldsrow * 66 + p) << 2) + ((q + (p >> 1)) & 3)) * 8);
                }
                const short* wp = ldsW + (size_t)(dy * 3 + dx) * COUT * 32;
#pragma unroll
                for (int nt = 0; nt < NT; ++nt) {
                    int n = nt * 16 + col;
                    bfr[nt] = *(const short8*)(wp +
                        (size_t)((n << 2) + ((q + (n >> 1)) & 3)) * 8);
                }
#pragma unroll
                for (int mt = 0; mt < 4; ++mt)
#pragma unroll
                    for (int nt = 0; nt < NT; ++nt)
                        acc[mt][nt] = __builtin_amdgcn_mfma_f32_16x16x32_bf16(
                            a[mt], bfr[nt], acc[mt][nt], 0, 0, 0);
            }
        }
        __syncthreads();                 // drains A(kc+1) prefetch: free by now
        if (kc + 1 < KC) {
            stageW(kc + 1);              // L2-resident, ~1.3k cy exposed
            __syncthreads();
        }
    }

    // ---- epilogue: D[m = mt*16 + q*4 + rr][n = nt*16 + col], leaky-relu, bf16 ----
    size_t obase = ((size_t)(b * 130 + row0 + 1 + out_row) * 258 + (w0h + 1)) * COUT;
#pragma unroll
    for (int nt = 0; nt < NT; ++nt) {
        int n = nt * 16 + col;
        float bv = bias[n];
#pragma unroll
        for (int mt = 0; mt < 4; ++mt) {
#pragma unroll
            for (int rr = 0; rr < 4; ++rr) {
                int m = mt * 16 + q * 4 + rr;
                float v = acc[mt][nt][rr] + bv;
                v = (v >= 0.f) ? v : LEAK * v;
                out[obase + (size_t)m * COUT + n] = (short)f2b(v);
            }
        }
    }
}

// conv6: 3x3, Cin=32 (halo layout), Cout=1, linear, fp32 out (flat [B,H,W])
__global__ void conv6_kernel(const short* __restrict__ x, const float* __restrict__ k,
                             const float* __restrict__ bias, float* __restrict__ out) {
    __shared__ float wk[288];
    int t = threadIdx.x;
    for (int i = t; i < 288; i += 256) wk[i] = k[i];
    __syncthreads();
    int idx = blockIdx.x * 256 + t;
    int w = idx & 255, h = (idx >> 8) & 127, b = idx >> 15;
    float acc = bias[0];
#pragma unroll
    for (int dy = 0; dy < 3; ++dy) {
#pragma unroll
        for (int dx = 0; dx < 3; ++dx) {
            const short* xp = x + ((size_t)(b * 130 + h + dy) * 258 + (w + dx)) * 32;
            const float* wp = wk + (dy * 3 + dx) * 32;
#pragma unroll
            for (int c8 = 0; c8 < 4; ++c8) {
                short8 v = *(const short8*)(xp + c8 * 8);
#pragma unroll
                for (int j = 0; j < 8; ++j)
                    acc += b2f((unsigned short)v[j]) * wp[c8 * 8 + j];
            }
        }
    }
    out[idx] = acc;
}

extern "C" void kernel_launch(void* const* d_in, const int* in_sizes, int n_in,
                              void* d_out, int out_size, void* d_ws, size_t ws_size,
                              hipStream_t stream) {
    const float* left  = (const float*)d_in[0];
    const float* right = (const float*)d_in[1];
    const float* pd    = (const float*)d_in[2];
    const float* k[6];
    const float* bb[6];
    for (int i = 0; i < 6; ++i) { k[i] = (const float*)d_in[3 + 2 * i]; bb[i] = (const float*)d_in[4 + 2 * i]; }

    char* ws = (char*)d_ws;
    // weights: [0, 1 MiB)
    short* wt1 = (short*)ws;
    short* wt2 = (short*)(ws + 368640);
    short* wt3 = (short*)(ws + 663552);
    short* wt4 = (short*)(ws + 884736);
    short* wt5 = (short*)(ws + 995328);
    // region A @1 MiB: vol(C=144) -> X2(128) -> X4(64); region B: X1(128) -> X3(96) -> X5(32)
    short* vol = (short*)(ws + 1048576);
    short* X1  = (short*)(ws + 1048576 + 77276160);
    short* X2  = vol;
    short* X3  = X1;
    short* X4  = vol;
    short* X5  = X1;

    auto hz = [&](short* buf, int C) {
        int blocks = (8 * 772 * (C >> 3) + 255) / 256;
        halo_zero_one<<<blocks, 256, 0, stream>>>(buf, C);
    };

    prep_kernel<<<4096, 256, 0, stream>>>(left, right, pd, vol);
    wconv_all<<<dim3(720, 5), 256, 0, stream>>>(k[0], k[1], k[2], k[3], k[4],
                                                wt1, wt2, wt3, wt4, wt5);
    hz(vol, 144);
    hz(X1, 128);

    conv3x3_kernel<5, 144, 128, 8, 2><<<512, 512, 0, stream>>>(vol, wt1, bb[0], X1);
    hz(X2, 128);   // region A: only after conv1 finished reading vol
    conv3x3_kernel<4, 128, 128, 8, 4><<<512, 512, 0, stream>>>(X1, wt2, bb[1], X2);
    hz(X3, 96);    // region B: only after conv2 finished reading X1
    conv3x3_kernel<4, 128,  96, 6, 4><<<512, 512, 0, stream>>>(X2, wt3, bb[2], X3);
    hz(X4, 64);    // region A: only after conv3 finished reading X2
    conv3x3_kernel<3,  96,  64, 4, 4><<<512, 512, 0, stream>>>(X3, wt4, bb[3], X4);
    hz(X5, 32);    // region B: only after conv4 finished reading X3
    conv3x3_kernel<2,  64,  32, 2, 4><<<512, 512, 0, stream>>>(X4, wt5, bb[4], X5);
    conv6_kernel<<<1024, 256, 0, stream>>>(X5, k[5], bb[5], (float*)d_out);
}